// Round 9
// baseline (82.374 us; speedup 1.0000x reference)
//
#include <hip/hip_runtime.h>
#include <math.h>

#define NT 256
#define RPB 64          // rows per block; 4 waves x one 16-row MFMA tile

typedef __attribute__((ext_vector_type(8))) short bf16x8;   // 8 bf16 = 4 VGPR
typedef __attribute__((ext_vector_type(4))) float f32x4;    // MFMA 16x16 acc

// jax.nn.softplus(x) = max(x,0) + log1p(exp(-|x|))
__device__ __forceinline__ float softplus_f(float v) {
    return fmaxf(v, 0.0f) + log1pf(expf(-fabsf(v)));
}
__device__ __forceinline__ unsigned short bfr(float f) {    // f32 -> bf16 RNE
    unsigned int u = __float_as_uint(f);
    u += 0x7FFFu + ((u >> 16) & 1u);
    return (unsigned short)(u >> 16);
}
__device__ __forceinline__ unsigned int bfpack(float a, float b) {
    return (unsigned int)bfr(a) | ((unsigned int)bfr(b) << 16);
}

// ---- ws layout (dword offsets) ----
// [0,3840):   WT bf16 [80 col][96 k]:
//   col<64,k<64:  sp(EX[k][col]) - sp(IN[k][col])
//   col<64,k=64+d: C[d][col] = M[d][col] - sp(w_in2hid[d][col])
//   64<=col<72,k<64: sp(w_hid2out[k][col-64]);  all else 0
// [3840,3904): a^4   [3904,3968): 1+a+a^2+a^3   [3968,4032): th_hid
// [4032,4056): dec_in[4] th_in[4] dec_out[8] th_out[8]

__global__ __launch_bounds__(NT) void twc_prep(
    const float* __restrict__ w_in2hid,
    const float* __restrict__ w_hid_IN,
    const float* __restrict__ w_hid_EX,
    const float* __restrict__ w_hid2out,
    const float* __restrict__ gj_w,
    const float* __restrict__ th_in,
    const float* __restrict__ dec_in,
    const float* __restrict__ th_hid,
    const float* __restrict__ dec_hid,
    const float* __restrict__ th_out,
    const float* __restrict__ dec_out,
    const int* __restrict__ gj_src,
    const int* __restrict__ gj_dst,
    float* __restrict__ ws)
{
    const int t = threadIdx.x;
    const int blk = blockIdx.x;
    unsigned short* wsS = (unsigned short*)ws;
    if (blk < 30) {
        const int e = blk * NT + t;              // 0..7679 = 80 cols x 96 k
        const int col = e / 96, k = e - col * 96;
        if (col < 64 && k >= 64 && k < 68) return;   // C entries: block 30 owns
        float v = 0.0f;
        if (col < 64 && k < 64)
            v = softplus_f(w_hid_EX[k * 64 + col]) - softplus_f(w_hid_IN[k * 64 + col]);
        else if (col >= 64 && col < 72 && k < 64)
            v = softplus_f(w_hid2out[k * 8 + (col - 64)]);
        wsS[e] = bfr(v);
    } else {
        __shared__ float sw[128];
        __shared__ int ssrc[128], sdst[128];
        if (t < 128) { sw[t] = softplus_f(gj_w[t]); ssrc[t] = gj_src[t]; sdst[t] = gj_dst[t]; }
        __syncthreads();
        if (t < 64) {
            const int j = t;
            float m0 = 0.f, m1 = 0.f, m2 = 0.f, m3 = 0.f, deg = 0.f;
            #pragma unroll 4
            for (int e = 0; e < 128; ++e) {
                const float w = (sdst[e] == j) ? sw[e] : 0.0f;
                deg += w;
                const int se = ssrc[e];
                m0 += (se == 0) ? w : 0.0f;
                m1 += (se == 1) ? w : 0.0f;
                m2 += (se == 2) ? w : 0.0f;
                m3 += (se == 3) ? w : 0.0f;
            }
            wsS[j * 96 + 64] = bfr(m0 - softplus_f(w_in2hid[0 * 64 + j]));
            wsS[j * 96 + 65] = bfr(m1 - softplus_f(w_in2hid[1 * 64 + j]));
            wsS[j * 96 + 66] = bfr(m2 - softplus_f(w_in2hid[2 * 64 + j]));
            wsS[j * 96 + 67] = bfr(m3 - softplus_f(w_in2hid[3 * 64 + j]));
            const float a  = dec_hid[j] - deg;
            const float a2 = a * a;
            ws[3840 + j] = a2 * a2;
            ws[3904 + j] = 1.0f + a + a2 + a2 * a;
            ws[3968 + j] = th_hid[j];
        }
        if (t < 4) { ws[4032 + t] = dec_in[t];  ws[4036 + t] = th_in[t]; }
        if (t < 8) { ws[4040 + t] = dec_out[t]; ws[4048 + t] = th_out[t]; }
    }
}

// main: no input staging; A/B fragments direct from global; LDS = epilogue buf only
__global__ __launch_bounds__(NT, 4) void twc_main(
    const float* __restrict__ x,
    const float* __restrict__ hidE0,
    const float* __restrict__ hidO0,
    const float* __restrict__ outE0,
    const float* __restrict__ ws,
    float* __restrict__ out, int B)
{
    __shared__ __align__(16) float buf[64 * 76];   // 19456 B
    const int t = threadIdx.x;
    const int l = t & 63, w = t >> 6;
    const int fr = l & 15, lg = l >> 4;
    const size_t rowBase = (size_t)blockIdx.x * RPB;
    const size_t Bs = (size_t)B;
    float4* out4 = (float4*)out;
    const float* wsf = ws;

    // ---- prefetch E0 (copy-out order) and outE0 (dense) ----
    float4 e0pre[4];
    float eo0pre[2];
    {
        const float4* gE0 = (const float4*)hidE0 + rowBase * 16;
        #pragma unroll
        for (int j = 0; j < 4; ++j) e0pre[j] = gE0[j * NT + t];
        #pragma unroll
        for (int j = 0; j < 2; ++j) eo0pre[j] = outE0[rowBase * 8 + j * NT + t];
    }

    // ---- A fragments direct from O0 / x (bf16-packed in registers) ----
    const int arow = w * 16 + fr;
    bf16x8 af0, af1, af2;
    {
        const float4* gO0r = (const float4*)hidO0 + (rowBase + arow) * 16;
        const float4 v0 = gO0r[lg * 2],     v1 = gO0r[lg * 2 + 1];      // s=0
        const float4 v2 = gO0r[8 + lg * 2], v3 = gO0r[8 + lg * 2 + 1];  // s=1
        unsigned int a0[4] = { bfpack(v0.x, v0.y), bfpack(v0.z, v0.w),
                               bfpack(v1.x, v1.y), bfpack(v1.z, v1.w) };
        unsigned int a1[4] = { bfpack(v2.x, v2.y), bfpack(v2.z, v2.w),
                               bfpack(v3.x, v3.y), bfpack(v3.z, v3.w) };
        af0 = *(const bf16x8*)a0;
        af1 = *(const bf16x8*)a1;
        unsigned int a2[4] = { 0u, 0u, 0u, 0u };
        if (lg == 0) {
            const float4 xr = ((const float4*)x)[rowBase + arow];
            a2[0] = bfpack(xr.x, xr.y);
            a2[1] = bfpack(xr.z, xr.w);
        }
        af2 = *(const bf16x8*)a2;
    }

    // ---- E_in / O_in (t<64; dense f4, exact f32 path) ----
    if (t < 64) {
        const float4 xv = ((const float4*)x)[rowBase + t];
        const float4 di = ((const float4*)ws)[1008];
        const float4 ti = ((const float4*)ws)[1009];
        float4 Ein, Oin;
        Ein.x = di.x * xv.x; Ein.y = di.y * xv.y; Ein.z = di.z * xv.z; Ein.w = di.w * xv.w;
        Oin.x = (Ein.x >= ti.x) ? Ein.x : 0.0f;
        Oin.y = (Ein.y >= ti.y) ? Ein.y : 0.0f;
        Oin.z = (Ein.z >= ti.z) ? Ein.z : 0.0f;
        Oin.w = (Ein.w >= ti.w) ? Ein.w : 0.0f;
        out4[Bs * 2 + rowBase + t] = Ein;
        out4[Bs * 3 + rowBase + t] = Oin;
    }

    // ---- MFMA: B fragments direct from ws (bf16, L1-resident) ----
    f32x4 acc[5];
    {
        const f32x4 z = {0.0f, 0.0f, 0.0f, 0.0f};
        #pragma unroll
        for (int ct = 0; ct < 5; ++ct) acc[ct] = z;
        const bf16x8* wsB = (const bf16x8*)ws;
        #pragma unroll
        for (int ct = 0; ct < 5; ++ct) {
            const int cb = (ct * 16 + fr) * 12 + lg;
            acc[ct] = __builtin_amdgcn_mfma_f32_16x16x32_bf16(af0, wsB[cb],     acc[ct], 0, 0, 0);
            acc[ct] = __builtin_amdgcn_mfma_f32_16x16x32_bf16(af1, wsB[cb + 4], acc[ct], 0, 0, 0);
            acc[ct] = __builtin_amdgcn_mfma_f32_16x16x32_bf16(af2, wsB[cb + 8], acc[ct], 0, 0, 0);
        }
    }

    // ---- epilogue: qs*I -> buf cols 0..63; h2o -> cols 64..71 ----
    {
        const int rowl = w * 16 + lg * 4;
        #pragma unroll
        for (int ct = 0; ct < 4; ++ct) {
            const int c = ct * 16 + fr;
            const float qs = wsf[3904 + c];
            #pragma unroll
            for (int r = 0; r < 4; ++r)
                buf[(rowl + r) * 76 + c] = qs * acc[ct][r];
        }
        if (fr < 8) {
            #pragma unroll
            for (int r = 0; r < 4; ++r)
                buf[(rowl + r) * 76 + 64 + fr] = acc[4][r];
        }
    }
    __syncthreads();

    // ---- copy-out: E = p4*E0 + buf (dense f4); O = gate(E); out-layer ----
    {
        const float4* th4 = (const float4*)ws + 992;
        const float4* p44 = (const float4*)ws + 960;
        #pragma unroll
        for (int j = 0; j < 4; ++j) {
            const int i = j * NT + t;
            const int row = i >> 4, c4 = i & 15;
            const float4 qi = *(const float4*)&buf[row * 76 + c4 * 4];
            const float4 p4 = p44[c4];
            const float4 e0 = e0pre[j];
            const float4 th = th4[c4];
            float4 E, O;
            E.x = fmaf(p4.x, e0.x, qi.x);
            E.y = fmaf(p4.y, e0.y, qi.y);
            E.z = fmaf(p4.z, e0.z, qi.z);
            E.w = fmaf(p4.w, e0.w, qi.w);
            O.x = (E.x >= th.x) ? E.x : 0.0f;
            O.y = (E.y >= th.y) ? E.y : 0.0f;
            O.z = (E.z >= th.z) ? E.z : 0.0f;
            O.w = (E.w >= th.w) ? E.w : 0.0f;
            out4[Bs * 4  + rowBase * 16 + i] = E;
            out4[Bs * 20 + rowBase * 16 + i] = O;
        }
        #pragma unroll
        for (int j = 0; j < 2; ++j) {
            const int idx = j * NT + t;          // 512 = 64 rows x 8
            const int row = idx >> 3, q = idx & 7;
            const float h  = buf[row * 76 + 64 + q];
            const float eo = fmaf(wsf[4040 + q], eo0pre[j], h);
            out[rowBase * 8 + idx]            = tanhf(eo);
            out[Bs * 144 + rowBase * 8 + idx] = eo;
            out[Bs * 152 + rowBase * 8 + idx] = (eo >= wsf[4048 + q]) ? eo : 0.0f;
        }
    }
}

extern "C" void kernel_launch(void* const* d_in, const int* in_sizes, int n_in,
                              void* d_out, int out_size, void* d_ws, size_t ws_size,
                              hipStream_t stream) {
    (void)n_in; (void)out_size; (void)ws_size;
    const float* x        = (const float*)d_in[0];
    const float* hidE0    = (const float*)d_in[1];
    const float* hidO0    = (const float*)d_in[2];
    const float* outE0    = (const float*)d_in[3];
    // d_in[4] (out_O0) unused by the reference
    const float* w_in2hid = (const float*)d_in[5];
    const float* w_hid_IN = (const float*)d_in[6];
    const float* w_hid_EX = (const float*)d_in[7];
    const float* w_hid2out= (const float*)d_in[8];
    const float* gj_w     = (const float*)d_in[9];
    const float* th_in    = (const float*)d_in[10];
    const float* dec_in   = (const float*)d_in[11];
    const float* th_hid   = (const float*)d_in[12];
    const float* dec_hid  = (const float*)d_in[13];
    const float* th_out   = (const float*)d_in[14];
    const float* dec_out  = (const float*)d_in[15];
    const int*   gj_src   = (const int*)d_in[16];
    const int*   gj_dst   = (const int*)d_in[17];
    float* out = (float*)d_out;
    float* ws  = (float*)d_ws;

    const int B = in_sizes[0] / 4;   // 262144, multiple of 64

    twc_prep<<<31, NT, 0, stream>>>(
        w_in2hid, w_hid_IN, w_hid_EX, w_hid2out, gj_w,
        th_in, dec_in, th_hid, dec_hid, th_out, dec_out,
        gj_src, gj_dst, ws);

    twc_main<<<B / RPB, NT, 0, stream>>>(x, hidE0, hidO0, outE0, ws, out, B);
}

// Round 11
// 67.879 us; speedup vs baseline: 1.2135x; 1.2135x over previous
//
#include <hip/hip_runtime.h>
#include <math.h>

#define NT 256
#define RPB 64          // rows per block; 4 waves x one 16-row MFMA tile

typedef __attribute__((ext_vector_type(8))) short bf16x8;   // 8 bf16 = 4 VGPR
typedef __attribute__((ext_vector_type(4))) float f32x4;    // MFMA 16x16 acc / native f4

// jax.nn.softplus(x) = max(x,0) + log1p(exp(-|x|))
__device__ __forceinline__ float softplus_f(float v) {
    return fmaxf(v, 0.0f) + log1pf(expf(-fabsf(v)));
}
__device__ __forceinline__ unsigned short bfr(float f) {    // f32 -> bf16 RNE
    unsigned int u = __float_as_uint(f);
    u += 0x7FFFu + ((u >> 16) & 1u);
    return (unsigned short)(u >> 16);
}
__device__ __forceinline__ unsigned int bfpack(float a, float b) {
    return (unsigned int)bfr(a) | ((unsigned int)bfr(b) << 16);
}
__device__ __forceinline__ void nt_store4(float4* p, float4 v) {
    f32x4 nv = { v.x, v.y, v.z, v.w };
    __builtin_nontemporal_store(nv, reinterpret_cast<f32x4*>(p));
}
__device__ __forceinline__ void nt_store1(float* p, float v) {
    __builtin_nontemporal_store(v, p);
}

// ---- ws layout (dword offsets) ----
// [0,3840):   WT bf16 [80 col][96 k]:
//   col<64,k<64:  sp(EX[k][col]) - sp(IN[k][col])
//   col<64,k=64+d: C[d][col] = M[d][col] - sp(w_in2hid[d][col])
//   64<=col<72,k<64: sp(w_hid2out[k][col-64]);  all else 0
// [3840,3904): a^4   [3904,3968): 1+a+a^2+a^3   [3968,4032): th_hid
// [4032,4056): dec_in[4] th_in[4] dec_out[8] th_out[8]

__global__ __launch_bounds__(NT) void twc_prep(
    const float* __restrict__ w_in2hid,
    const float* __restrict__ w_hid_IN,
    const float* __restrict__ w_hid_EX,
    const float* __restrict__ w_hid2out,
    const float* __restrict__ gj_w,
    const float* __restrict__ th_in,
    const float* __restrict__ dec_in,
    const float* __restrict__ th_hid,
    const float* __restrict__ dec_hid,
    const float* __restrict__ th_out,
    const float* __restrict__ dec_out,
    const int* __restrict__ gj_src,
    const int* __restrict__ gj_dst,
    float* __restrict__ ws)
{
    const int t = threadIdx.x;
    const int blk = blockIdx.x;
    unsigned short* wsS = (unsigned short*)ws;
    if (blk < 30) {
        const int e = blk * NT + t;              // 0..7679 = 80 cols x 96 k
        const int col = e / 96, k = e - col * 96;
        if (col < 64 && k >= 64 && k < 68) return;   // C entries: block 30 owns
        float v = 0.0f;
        if (col < 64 && k < 64)
            v = softplus_f(w_hid_EX[k * 64 + col]) - softplus_f(w_hid_IN[k * 64 + col]);
        else if (col >= 64 && col < 72 && k < 64)
            v = softplus_f(w_hid2out[k * 8 + (col - 64)]);
        wsS[e] = bfr(v);
    } else {
        __shared__ float sw[128];
        __shared__ int ssrc[128], sdst[128];
        if (t < 128) { sw[t] = softplus_f(gj_w[t]); ssrc[t] = gj_src[t]; sdst[t] = gj_dst[t]; }
        __syncthreads();
        if (t < 64) {
            const int j = t;
            float m0 = 0.f, m1 = 0.f, m2 = 0.f, m3 = 0.f, deg = 0.f;
            #pragma unroll 4
            for (int e = 0; e < 128; ++e) {
                const float w = (sdst[e] == j) ? sw[e] : 0.0f;
                deg += w;
                const int se = ssrc[e];
                m0 += (se == 0) ? w : 0.0f;
                m1 += (se == 1) ? w : 0.0f;
                m2 += (se == 2) ? w : 0.0f;
                m3 += (se == 3) ? w : 0.0f;
            }
            wsS[j * 96 + 64] = bfr(m0 - softplus_f(w_in2hid[0 * 64 + j]));
            wsS[j * 96 + 65] = bfr(m1 - softplus_f(w_in2hid[1 * 64 + j]));
            wsS[j * 96 + 66] = bfr(m2 - softplus_f(w_in2hid[2 * 64 + j]));
            wsS[j * 96 + 67] = bfr(m3 - softplus_f(w_in2hid[3 * 64 + j]));
            const float a  = dec_hid[j] - deg;
            const float a2 = a * a;
            ws[3840 + j] = a2 * a2;
            ws[3904 + j] = 1.0f + a + a2 + a2 * a;
            ws[3968 + j] = th_hid[j];
        }
        if (t < 4) { ws[4032 + t] = dec_in[t];  ws[4036 + t] = th_in[t]; }
        if (t < 8) { ws[4040 + t] = dec_out[t]; ws[4048 + t] = th_out[t]; }
    }
}

// main: no input staging; A/B fragments direct from global; LDS = epilogue buf only
__global__ __launch_bounds__(NT, 4) void twc_main(
    const float* __restrict__ x,
    const float* __restrict__ hidE0,
    const float* __restrict__ hidO0,
    const float* __restrict__ outE0,
    const float* __restrict__ ws,
    float* __restrict__ out, int B)
{
    __shared__ __align__(16) float buf[64 * 76];   // 19456 B
    const int t = threadIdx.x;
    const int l = t & 63, w = t >> 6;
    const int fr = l & 15, lg = l >> 4;
    const size_t rowBase = (size_t)blockIdx.x * RPB;
    const size_t Bs = (size_t)B;
    float4* out4 = (float4*)out;
    const float* wsf = ws;

    // ---- prefetch E0 (copy-out order) and outE0 (dense) ----
    float4 e0pre[4];
    float eo0pre[2];
    {
        const float4* gE0 = (const float4*)hidE0 + rowBase * 16;
        #pragma unroll
        for (int j = 0; j < 4; ++j) e0pre[j] = gE0[j * NT + t];
        #pragma unroll
        for (int j = 0; j < 2; ++j) eo0pre[j] = outE0[rowBase * 8 + j * NT + t];
    }

    // ---- A fragments direct from O0 / x (bf16-packed in registers) ----
    const int arow = w * 16 + fr;
    bf16x8 af0, af1, af2;
    {
        const float4* gO0r = (const float4*)hidO0 + (rowBase + arow) * 16;
        const float4 v0 = gO0r[lg * 2],     v1 = gO0r[lg * 2 + 1];      // s=0
        const float4 v2 = gO0r[8 + lg * 2], v3 = gO0r[8 + lg * 2 + 1];  // s=1
        unsigned int a0[4] = { bfpack(v0.x, v0.y), bfpack(v0.z, v0.w),
                               bfpack(v1.x, v1.y), bfpack(v1.z, v1.w) };
        unsigned int a1[4] = { bfpack(v2.x, v2.y), bfpack(v2.z, v2.w),
                               bfpack(v3.x, v3.y), bfpack(v3.z, v3.w) };
        af0 = *(const bf16x8*)a0;
        af1 = *(const bf16x8*)a1;
        unsigned int a2[4] = { 0u, 0u, 0u, 0u };
        if (lg == 0) {
            const float4 xr = ((const float4*)x)[rowBase + arow];
            a2[0] = bfpack(xr.x, xr.y);
            a2[1] = bfpack(xr.z, xr.w);
        }
        af2 = *(const bf16x8*)a2;
    }

    // ---- E_in / O_in (t<64; dense f4, exact f32 path) ----
    if (t < 64) {
        const float4 xv = ((const float4*)x)[rowBase + t];
        const float4 di = ((const float4*)ws)[1008];
        const float4 ti = ((const float4*)ws)[1009];
        float4 Ein, Oin;
        Ein.x = di.x * xv.x; Ein.y = di.y * xv.y; Ein.z = di.z * xv.z; Ein.w = di.w * xv.w;
        Oin.x = (Ein.x >= ti.x) ? Ein.x : 0.0f;
        Oin.y = (Ein.y >= ti.y) ? Ein.y : 0.0f;
        Oin.z = (Ein.z >= ti.z) ? Ein.z : 0.0f;
        Oin.w = (Ein.w >= ti.w) ? Ein.w : 0.0f;
        nt_store4(&out4[Bs * 2 + rowBase + t], Ein);
        nt_store4(&out4[Bs * 3 + rowBase + t], Oin);
    }

    // ---- MFMA: B fragments direct from ws (bf16, L1-resident) ----
    f32x4 acc[5];
    {
        const f32x4 z = {0.0f, 0.0f, 0.0f, 0.0f};
        #pragma unroll
        for (int ct = 0; ct < 5; ++ct) acc[ct] = z;
        const bf16x8* wsB = (const bf16x8*)ws;
        #pragma unroll
        for (int ct = 0; ct < 5; ++ct) {
            const int cb = (ct * 16 + fr) * 12 + lg;
            acc[ct] = __builtin_amdgcn_mfma_f32_16x16x32_bf16(af0, wsB[cb],     acc[ct], 0, 0, 0);
            acc[ct] = __builtin_amdgcn_mfma_f32_16x16x32_bf16(af1, wsB[cb + 4], acc[ct], 0, 0, 0);
            acc[ct] = __builtin_amdgcn_mfma_f32_16x16x32_bf16(af2, wsB[cb + 8], acc[ct], 0, 0, 0);
        }
    }

    // ---- epilogue: qs*I -> buf cols 0..63; h2o -> cols 64..71 ----
    {
        const int rowl = w * 16 + lg * 4;
        #pragma unroll
        for (int ct = 0; ct < 4; ++ct) {
            const int c = ct * 16 + fr;
            const float qs = wsf[3904 + c];
            #pragma unroll
            for (int r = 0; r < 4; ++r)
                buf[(rowl + r) * 76 + c] = qs * acc[ct][r];
        }
        if (fr < 8) {
            #pragma unroll
            for (int r = 0; r < 4; ++r)
                buf[(rowl + r) * 76 + 64 + fr] = acc[4][r];
        }
    }
    __syncthreads();

    // ---- copy-out: E = p4*E0 + buf (dense f4, nt); O = gate(E); out-layer ----
    {
        const float4* th4 = (const float4*)ws + 992;
        const float4* p44 = (const float4*)ws + 960;
        #pragma unroll
        for (int j = 0; j < 4; ++j) {
            const int i = j * NT + t;
            const int row = i >> 4, c4 = i & 15;
            const float4 qi = *(const float4*)&buf[row * 76 + c4 * 4];
            const float4 p4 = p44[c4];
            const float4 e0 = e0pre[j];
            const float4 th = th4[c4];
            float4 E, O;
            E.x = fmaf(p4.x, e0.x, qi.x);
            E.y = fmaf(p4.y, e0.y, qi.y);
            E.z = fmaf(p4.z, e0.z, qi.z);
            E.w = fmaf(p4.w, e0.w, qi.w);
            O.x = (E.x >= th.x) ? E.x : 0.0f;
            O.y = (E.y >= th.y) ? E.y : 0.0f;
            O.z = (E.z >= th.z) ? E.z : 0.0f;
            O.w = (E.w >= th.w) ? E.w : 0.0f;
            nt_store4(&out4[Bs * 4  + rowBase * 16 + i], E);
            nt_store4(&out4[Bs * 20 + rowBase * 16 + i], O);
        }
        #pragma unroll
        for (int j = 0; j < 2; ++j) {
            const int idx = j * NT + t;          // 512 = 64 rows x 8
            const int row = idx >> 3, q = idx & 7;
            const float h  = buf[row * 76 + 64 + q];
            const float eo = fmaf(wsf[4040 + q], eo0pre[j], h);
            nt_store1(&out[rowBase * 8 + idx], tanhf(eo));
            nt_store1(&out[Bs * 144 + rowBase * 8 + idx], eo);
            nt_store1(&out[Bs * 152 + rowBase * 8 + idx], (eo >= wsf[4048 + q]) ? eo : 0.0f);
        }
    }
}

extern "C" void kernel_launch(void* const* d_in, const int* in_sizes, int n_in,
                              void* d_out, int out_size, void* d_ws, size_t ws_size,
                              hipStream_t stream) {
    (void)n_in; (void)out_size; (void)ws_size;
    const float* x        = (const float*)d_in[0];
    const float* hidE0    = (const float*)d_in[1];
    const float* hidO0    = (const float*)d_in[2];
    const float* outE0    = (const float*)d_in[3];
    // d_in[4] (out_O0) unused by the reference
    const float* w_in2hid = (const float*)d_in[5];
    const float* w_hid_IN = (const float*)d_in[6];
    const float* w_hid_EX = (const float*)d_in[7];
    const float* w_hid2out= (const float*)d_in[8];
    const float* gj_w     = (const float*)d_in[9];
    const float* th_in    = (const float*)d_in[10];
    const float* dec_in   = (const float*)d_in[11];
    const float* th_hid   = (const float*)d_in[12];
    const float* dec_hid  = (const float*)d_in[13];
    const float* th_out   = (const float*)d_in[14];
    const float* dec_out  = (const float*)d_in[15];
    const int*   gj_src   = (const int*)d_in[16];
    const int*   gj_dst   = (const int*)d_in[17];
    float* out = (float*)d_out;
    float* ws  = (float*)d_ws;

    const int B = in_sizes[0] / 4;   // 262144, multiple of 64

    twc_prep<<<31, NT, 0, stream>>>(
        w_in2hid, w_hid_IN, w_hid_EX, w_hid2out, gj_w,
        th_in, dec_in, th_hid, dec_hid, th_out, dec_out,
        gj_src, gj_dst, ws);

    twc_main<<<B / RPB, NT, 0, stream>>>(x, hidE0, hidO0, outE0, ws, out, B);
}

// Round 12
// 65.627 us; speedup vs baseline: 1.2552x; 1.0343x over previous
//
#include <hip/hip_runtime.h>
#include <math.h>

#define NT 256
#define RPB 128         // rows per block; 4 waves x two 16-row MFMA tiles

typedef __attribute__((ext_vector_type(8))) short bf16x8;   // 8 bf16 = 4 VGPR
typedef __attribute__((ext_vector_type(4))) float f32x4;    // MFMA 16x16 acc / native f4

// jax.nn.softplus(x) = max(x,0) + log1p(exp(-|x|))
__device__ __forceinline__ float softplus_f(float v) {
    return fmaxf(v, 0.0f) + log1pf(expf(-fabsf(v)));
}
__device__ __forceinline__ unsigned short bfr(float f) {    // f32 -> bf16 RNE
    unsigned int u = __float_as_uint(f);
    u += 0x7FFFu + ((u >> 16) & 1u);
    return (unsigned short)(u >> 16);
}
__device__ __forceinline__ unsigned int bfpack(float a, float b) {
    return (unsigned int)bfr(a) | ((unsigned int)bfr(b) << 16);
}
__device__ __forceinline__ void nt_store4(float4* p, float4 v) {
    f32x4 nv = { v.x, v.y, v.z, v.w };
    __builtin_nontemporal_store(nv, reinterpret_cast<f32x4*>(p));
}
__device__ __forceinline__ void nt_store1(float* p, float v) {
    __builtin_nontemporal_store(v, p);
}

// ---- ws layout (dword offsets) ----
// [0,3840):   WT bf16 [80 col][96 k]:
//   col<64,k<64:  sp(EX[k][col]) - sp(IN[k][col])
//   col<64,k=64+d: C[d][col] = M[d][col] - sp(w_in2hid[d][col])
//   64<=col<72,k<64: sp(w_hid2out[k][col-64]);  all else 0
// [3840,3904): a^4   [3904,3968): 1+a+a^2+a^3   [3968,4032): th_hid
// [4032,4056): dec_in[4] th_in[4] dec_out[8] th_out[8]

__global__ __launch_bounds__(NT) void twc_prep(
    const float* __restrict__ w_in2hid,
    const float* __restrict__ w_hid_IN,
    const float* __restrict__ w_hid_EX,
    const float* __restrict__ w_hid2out,
    const float* __restrict__ gj_w,
    const float* __restrict__ th_in,
    const float* __restrict__ dec_in,
    const float* __restrict__ th_hid,
    const float* __restrict__ dec_hid,
    const float* __restrict__ th_out,
    const float* __restrict__ dec_out,
    const int* __restrict__ gj_src,
    const int* __restrict__ gj_dst,
    float* __restrict__ ws)
{
    const int t = threadIdx.x;
    const int blk = blockIdx.x;
    unsigned short* wsS = (unsigned short*)ws;
    if (blk < 30) {
        const int e = blk * NT + t;              // 0..7679 = 80 cols x 96 k
        const int col = e / 96, k = e - col * 96;
        if (col < 64 && k >= 64 && k < 68) return;   // C entries: block 30 owns
        float v = 0.0f;
        if (col < 64 && k < 64)
            v = softplus_f(w_hid_EX[k * 64 + col]) - softplus_f(w_hid_IN[k * 64 + col]);
        else if (col >= 64 && col < 72 && k < 64)
            v = softplus_f(w_hid2out[k * 8 + (col - 64)]);
        wsS[e] = bfr(v);
    } else {
        __shared__ float sw[128];
        __shared__ int ssrc[128], sdst[128];
        if (t < 128) { sw[t] = softplus_f(gj_w[t]); ssrc[t] = gj_src[t]; sdst[t] = gj_dst[t]; }
        __syncthreads();
        if (t < 64) {
            const int j = t;
            float m0 = 0.f, m1 = 0.f, m2 = 0.f, m3 = 0.f, deg = 0.f;
            #pragma unroll 4
            for (int e = 0; e < 128; ++e) {
                const float w = (sdst[e] == j) ? sw[e] : 0.0f;
                deg += w;
                const int se = ssrc[e];
                m0 += (se == 0) ? w : 0.0f;
                m1 += (se == 1) ? w : 0.0f;
                m2 += (se == 2) ? w : 0.0f;
                m3 += (se == 3) ? w : 0.0f;
            }
            wsS[j * 96 + 64] = bfr(m0 - softplus_f(w_in2hid[0 * 64 + j]));
            wsS[j * 96 + 65] = bfr(m1 - softplus_f(w_in2hid[1 * 64 + j]));
            wsS[j * 96 + 66] = bfr(m2 - softplus_f(w_in2hid[2 * 64 + j]));
            wsS[j * 96 + 67] = bfr(m3 - softplus_f(w_in2hid[3 * 64 + j]));
            const float a  = dec_hid[j] - deg;
            const float a2 = a * a;
            ws[3840 + j] = a2 * a2;
            ws[3904 + j] = 1.0f + a + a2 + a2 * a;
            ws[3968 + j] = th_hid[j];
        }
        if (t < 4) { ws[4032 + t] = dec_in[t];  ws[4036 + t] = th_in[t]; }
        if (t < 8) { ws[4040 + t] = dec_out[t]; ws[4048 + t] = th_out[t]; }
    }
}

// main: two 64-row tiles per block; B fragments loaded once, reused for both
__global__ __launch_bounds__(NT, 2) void twc_main(
    const float* __restrict__ x,
    const float* __restrict__ hidE0,
    const float* __restrict__ hidO0,
    const float* __restrict__ outE0,
    const float* __restrict__ ws,
    float* __restrict__ out, int B)
{
    __shared__ __align__(16) float buf[64 * 76];   // 19456 B, reused per tile
    const int t = threadIdx.x;
    const int l = t & 63, w = t >> 6;
    const int fr = l & 15, lg = l >> 4;
    const size_t rowBase = (size_t)blockIdx.x * RPB;
    const size_t Bs = (size_t)B;
    float4* out4 = (float4*)out;
    const float* wsf = ws;

    // ---- prefetch E0 (copy-out order, both tiles) and outE0 ----
    float4 e0pre[8];
    float eo0pre[4];
    {
        const float4* gE0 = (const float4*)hidE0 + rowBase * 16;
        #pragma unroll
        for (int j = 0; j < 8; ++j) e0pre[j] = gE0[j * NT + t];
        #pragma unroll
        for (int j = 0; j < 4; ++j) eo0pre[j] = outE0[rowBase * 8 + j * NT + t];
    }

    // ---- A fragments for both tiles (bf16-packed in registers) ----
    const int arow = w * 16 + fr;
    bf16x8 a0s0, a0s1, a0s2, a1s0, a1s1, a1s2;
    {
        const float4* g0 = (const float4*)hidO0 + (rowBase + arow) * 16;
        const float4* g1 = (const float4*)hidO0 + (rowBase + 64 + arow) * 16;
        const float4 u0 = g0[lg * 2],     u1 = g0[lg * 2 + 1];
        const float4 u2 = g0[8 + lg * 2], u3 = g0[8 + lg * 2 + 1];
        const float4 v0 = g1[lg * 2],     v1 = g1[lg * 2 + 1];
        const float4 v2 = g1[8 + lg * 2], v3 = g1[8 + lg * 2 + 1];
        unsigned int p0[4] = { bfpack(u0.x, u0.y), bfpack(u0.z, u0.w),
                               bfpack(u1.x, u1.y), bfpack(u1.z, u1.w) };
        unsigned int p1[4] = { bfpack(u2.x, u2.y), bfpack(u2.z, u2.w),
                               bfpack(u3.x, u3.y), bfpack(u3.z, u3.w) };
        unsigned int p2[4] = { bfpack(v0.x, v0.y), bfpack(v0.z, v0.w),
                               bfpack(v1.x, v1.y), bfpack(v1.z, v1.w) };
        unsigned int p3[4] = { bfpack(v2.x, v2.y), bfpack(v2.z, v2.w),
                               bfpack(v3.x, v3.y), bfpack(v3.z, v3.w) };
        a0s0 = *(const bf16x8*)p0;  a0s1 = *(const bf16x8*)p1;
        a1s0 = *(const bf16x8*)p2;  a1s1 = *(const bf16x8*)p3;
        unsigned int q0[4] = { 0u, 0u, 0u, 0u };
        unsigned int q1[4] = { 0u, 0u, 0u, 0u };
        if (lg == 0) {
            const float4 x0 = ((const float4*)x)[rowBase + arow];
            const float4 x1 = ((const float4*)x)[rowBase + 64 + arow];
            q0[0] = bfpack(x0.x, x0.y);  q0[1] = bfpack(x0.z, x0.w);
            q1[0] = bfpack(x1.x, x1.y);  q1[1] = bfpack(x1.z, x1.w);
        }
        a0s2 = *(const bf16x8*)q0;  a1s2 = *(const bf16x8*)q1;
    }

    // ---- E_in / O_in (t<128; dense f4, exact f32 path) ----
    if (t < 128) {
        const float4 xv = ((const float4*)x)[rowBase + t];
        const float4 di = ((const float4*)ws)[1008];
        const float4 ti = ((const float4*)ws)[1009];
        float4 Ein, Oin;
        Ein.x = di.x * xv.x; Ein.y = di.y * xv.y; Ein.z = di.z * xv.z; Ein.w = di.w * xv.w;
        Oin.x = (Ein.x >= ti.x) ? Ein.x : 0.0f;
        Oin.y = (Ein.y >= ti.y) ? Ein.y : 0.0f;
        Oin.z = (Ein.z >= ti.z) ? Ein.z : 0.0f;
        Oin.w = (Ein.w >= ti.w) ? Ein.w : 0.0f;
        nt_store4(&out4[Bs * 2 + rowBase + t], Ein);
        nt_store4(&out4[Bs * 3 + rowBase + t], Oin);
    }

    // ---- MFMA: B fragments loaded once, used by both tiles ----
    f32x4 acc0[5], acc1[5];
    {
        const f32x4 z = {0.0f, 0.0f, 0.0f, 0.0f};
        #pragma unroll
        for (int ct = 0; ct < 5; ++ct) { acc0[ct] = z; acc1[ct] = z; }
        const bf16x8* wsB = (const bf16x8*)ws;
        #pragma unroll
        for (int ct = 0; ct < 5; ++ct) {
            const int cb = (ct * 16 + fr) * 12 + lg;
            const bf16x8 b0 = wsB[cb], b1 = wsB[cb + 4], b2 = wsB[cb + 8];
            acc0[ct] = __builtin_amdgcn_mfma_f32_16x16x32_bf16(a0s0, b0, acc0[ct], 0, 0, 0);
            acc0[ct] = __builtin_amdgcn_mfma_f32_16x16x32_bf16(a0s1, b1, acc0[ct], 0, 0, 0);
            acc0[ct] = __builtin_amdgcn_mfma_f32_16x16x32_bf16(a0s2, b2, acc0[ct], 0, 0, 0);
            acc1[ct] = __builtin_amdgcn_mfma_f32_16x16x32_bf16(a1s0, b0, acc1[ct], 0, 0, 0);
            acc1[ct] = __builtin_amdgcn_mfma_f32_16x16x32_bf16(a1s1, b1, acc1[ct], 0, 0, 0);
            acc1[ct] = __builtin_amdgcn_mfma_f32_16x16x32_bf16(a1s2, b2, acc1[ct], 0, 0, 0);
        }
    }

    const float4* th4 = (const float4*)ws + 992;
    const float4* p44 = (const float4*)ws + 960;
    const int rowl = w * 16 + lg * 4;

    // ================= tile 0 =================
    {
        #pragma unroll
        for (int ct = 0; ct < 4; ++ct) {
            const int c = ct * 16 + fr;
            const float qs = wsf[3904 + c];
            #pragma unroll
            for (int r = 0; r < 4; ++r)
                buf[(rowl + r) * 76 + c] = qs * acc0[ct][r];
        }
        if (fr < 8) {
            #pragma unroll
            for (int r = 0; r < 4; ++r)
                buf[(rowl + r) * 76 + 64 + fr] = acc0[4][r];
        }
    }
    __syncthreads();
    {
        #pragma unroll
        for (int j = 0; j < 4; ++j) {
            const int i = j * NT + t;
            const int row = i >> 4, c4 = i & 15;
            const float4 qi = *(const float4*)&buf[row * 76 + c4 * 4];
            const float4 p4 = p44[c4];
            const float4 e0 = e0pre[j];
            const float4 th = th4[c4];
            float4 E, O;
            E.x = fmaf(p4.x, e0.x, qi.x);
            E.y = fmaf(p4.y, e0.y, qi.y);
            E.z = fmaf(p4.z, e0.z, qi.z);
            E.w = fmaf(p4.w, e0.w, qi.w);
            O.x = (E.x >= th.x) ? E.x : 0.0f;
            O.y = (E.y >= th.y) ? E.y : 0.0f;
            O.z = (E.z >= th.z) ? E.z : 0.0f;
            O.w = (E.w >= th.w) ? E.w : 0.0f;
            nt_store4(&out4[Bs * 4  + rowBase * 16 + i], E);
            nt_store4(&out4[Bs * 20 + rowBase * 16 + i], O);
        }
        #pragma unroll
        for (int j = 0; j < 2; ++j) {
            const int idx = j * NT + t;          // 512 = 64 rows x 8
            const int row = idx >> 3, q = idx & 7;
            const float h  = buf[row * 76 + 64 + q];
            const float eo = fmaf(wsf[4040 + q], eo0pre[j], h);
            nt_store1(&out[rowBase * 8 + idx], tanhf(eo));
            nt_store1(&out[Bs * 144 + rowBase * 8 + idx], eo);
            nt_store1(&out[Bs * 152 + rowBase * 8 + idx], (eo >= wsf[4048 + q]) ? eo : 0.0f);
        }
    }
    __syncthreads();   // tile-0 reads done before buf overwrite

    // ================= tile 1 =================
    {
        #pragma unroll
        for (int ct = 0; ct < 4; ++ct) {
            const int c = ct * 16 + fr;
            const float qs = wsf[3904 + c];
            #pragma unroll
            for (int r = 0; r < 4; ++r)
                buf[(rowl + r) * 76 + c] = qs * acc1[ct][r];
        }
        if (fr < 8) {
            #pragma unroll
            for (int r = 0; r < 4; ++r)
                buf[(rowl + r) * 76 + 64 + fr] = acc1[4][r];
        }
    }
    __syncthreads();
    {
        const size_t rb1 = rowBase + 64;
        #pragma unroll
        for (int j = 0; j < 4; ++j) {
            const int i = j * NT + t;
            const int row = i >> 4, c4 = i & 15;
            const float4 qi = *(const float4*)&buf[row * 76 + c4 * 4];
            const float4 p4 = p44[c4];
            const float4 e0 = e0pre[4 + j];
            const float4 th = th4[c4];
            float4 E, O;
            E.x = fmaf(p4.x, e0.x, qi.x);
            E.y = fmaf(p4.y, e0.y, qi.y);
            E.z = fmaf(p4.z, e0.z, qi.z);
            E.w = fmaf(p4.w, e0.w, qi.w);
            O.x = (E.x >= th.x) ? E.x : 0.0f;
            O.y = (E.y >= th.y) ? E.y : 0.0f;
            O.z = (E.z >= th.z) ? E.z : 0.0f;
            O.w = (E.w >= th.w) ? E.w : 0.0f;
            nt_store4(&out4[Bs * 4  + rb1 * 16 + i], E);
            nt_store4(&out4[Bs * 20 + rb1 * 16 + i], O);
        }
        #pragma unroll
        for (int j = 0; j < 2; ++j) {
            const int idx = j * NT + t;
            const int row = idx >> 3, q = idx & 7;
            const float h  = buf[row * 76 + 64 + q];
            const float eo = fmaf(wsf[4040 + q], eo0pre[2 + j], h);
            nt_store1(&out[rb1 * 8 + idx], tanhf(eo));
            nt_store1(&out[Bs * 144 + rb1 * 8 + idx], eo);
            nt_store1(&out[Bs * 152 + rb1 * 8 + idx], (eo >= wsf[4048 + q]) ? eo : 0.0f);
        }
    }
}

extern "C" void kernel_launch(void* const* d_in, const int* in_sizes, int n_in,
                              void* d_out, int out_size, void* d_ws, size_t ws_size,
                              hipStream_t stream) {
    (void)n_in; (void)out_size; (void)ws_size;
    const float* x        = (const float*)d_in[0];
    const float* hidE0    = (const float*)d_in[1];
    const float* hidO0    = (const float*)d_in[2];
    const float* outE0    = (const float*)d_in[3];
    // d_in[4] (out_O0) unused by the reference
    const float* w_in2hid = (const float*)d_in[5];
    const float* w_hid_IN = (const float*)d_in[6];
    const float* w_hid_EX = (const float*)d_in[7];
    const float* w_hid2out= (const float*)d_in[8];
    const float* gj_w     = (const float*)d_in[9];
    const float* th_in    = (const float*)d_in[10];
    const float* dec_in   = (const float*)d_in[11];
    const float* th_hid   = (const float*)d_in[12];
    const float* dec_hid  = (const float*)d_in[13];
    const float* th_out   = (const float*)d_in[14];
    const float* dec_out  = (const float*)d_in[15];
    const int*   gj_src   = (const int*)d_in[16];
    const int*   gj_dst   = (const int*)d_in[17];
    float* out = (float*)d_out;
    float* ws  = (float*)d_ws;

    const int B = in_sizes[0] / 4;   // 262144, multiple of 128

    twc_prep<<<31, NT, 0, stream>>>(
        w_in2hid, w_hid_IN, w_hid_EX, w_hid2out, gj_w,
        th_in, dec_in, th_hid, dec_hid, th_out, dec_out,
        gj_src, gj_dst, ws);

    twc_main<<<B / RPB, NT, 0, stream>>>(x, hidE0, hidO0, outE0, ws, out, B);
}